// Round 18
// baseline (146.661 us; speedup 1.0000x reference)
//
#include <hip/hip_runtime.h>
#include <cstddef>
#include <cstdint>

#define HWT   3136        // 56*56
#define WIMG  56
#define CCH   256
#define NH    8
#define QKV_ELEMS (16 * HWT * 32)   // per-tensor q/k/v elements
#define SCALE 0.17677669529663687f  // 32^-0.5
#define PAD   40                    // padded LDS row (elems): 80B, 16B-aligned

typedef __attribute__((ext_vector_type(8))) short short8;
typedef __attribute__((ext_vector_type(4))) short short4v;
typedef __attribute__((ext_vector_type(4))) float f32x4;
typedef _Float16 half2v __attribute__((ext_vector_type(2)));
typedef _Float16 half4v __attribute__((ext_vector_type(4)));
typedef _Float16 half8v __attribute__((ext_vector_type(8)));

#if defined(__has_builtin)
#if __has_builtin(__builtin_amdgcn_fdot2)
#define HAVE_FDOT2 1
#endif
#endif
#ifndef HAVE_FDOT2
#define HAVE_FDOT2 0
#endif

__device__ __forceinline__ ushort f2bf(float f) {
  union { float f; uint32_t u; } v; v.f = f;
  uint32_t u = v.u;
  u += 0x7fffu + ((u >> 16) & 1u);   // round-to-nearest-even
  return (ushort)(u >> 16);
}

// ---------------------------------------------------------------------------
// gemm_qkv: fused prep + qkv GEMM. Grid (49, 13, 2).
//   y==12: src16 builder slice (z==0 only).
//   y<12 : BM=64 x BN=64 x BK=32 MFMA GEMM, A=qkv_w f32 (reg-converted),
//          B=x f32 (b,c,hw) reg-transposed+converted into padded LDS.
//   Epilogue -> fp16 q*scale / kT8 / v.
// R18 PROBE: launched 5x (idempotent rewrite of qh/kt8/vh/src16).
// ---------------------------------------------------------------------------
__global__ __launch_bounds__(256) void gemm_qkv_k(
    const float* __restrict__ x, const float* __restrict__ qkv_w,
    const float* __restrict__ qkv_b, _Float16* __restrict__ qh,
    ushort* __restrict__ src16) {
  if (blockIdx.y == 12) {            // src16 builder slice
    if (blockIdx.z == 0) {
      for (int e = blockIdx.x * 256 + threadIdx.x; e < 2500 * 49;
           e += 49 * 256) {
        int sp = e / 2500;
        int pos = e - sp * 2500;
        int si = pos / 50;
        int sj = pos - si * 50;
        src16[e] = (ushort)((si + sp / 7) * WIMG + sj + sp % 7);
      }
    }
    return;
  }

  __shared__ ushort Alds[64 * PAD];
  __shared__ ushort Blds[64 * PAD];

  const int t  = threadIdx.x;
  const int m0 = blockIdx.y * 64;
  const int n0 = blockIdx.x * 64;
  const int b  = blockIdx.z;

  const float* xb = x + (size_t)b * CCH * HWT;

  const int lane = t & 63, wid = t >> 6;
  const int wm = (wid >> 1) * 32, wn = (wid & 1) * 32;
  const int lrow = lane & 15;
  const int cw8  = (lane >> 4) * 8;

  const int srow = t >> 2;   // 0..63
  const int scs  = t & 3;    // 8-elem chunk

  f32x4 acc[2][2];
#pragma unroll
  for (int i = 0; i < 2; ++i)
#pragma unroll
    for (int j = 0; j < 2; ++j) acc[i][j] = (f32x4){0.f, 0.f, 0.f, 0.f};

  for (int k0 = 0; k0 < CCH; k0 += 32) {
    __syncthreads();
    // A stage: qkv_w[m0+srow][k0+scs*8 ..+8] f32 -> bf16
    {
      const float* ap = qkv_w + (size_t)(m0 + srow) * CCH + k0 + scs * 8;
      const float4 v0 = *(const float4*)ap;
      const float4 v1 = *(const float4*)(ap + 4);
      ushort tmp[8];
      tmp[0] = f2bf(v0.x); tmp[1] = f2bf(v0.y);
      tmp[2] = f2bf(v0.z); tmp[3] = f2bf(v0.w);
      tmp[4] = f2bf(v1.x); tmp[5] = f2bf(v1.y);
      tmp[6] = f2bf(v1.z); tmp[7] = f2bf(v1.w);
      *(short8*)&Alds[srow * PAD + scs * 8] = *(const short8*)tmp;
    }
    // B stage (transpose): x[k0+scs*8+i][n0+srow] f32, i=0..7 -> bf16
    {
      const float* bp = xb + (size_t)(k0 + scs * 8) * HWT + n0 + srow;
      ushort tmp[8];
#pragma unroll
      for (int i = 0; i < 8; ++i) tmp[i] = f2bf(bp[(size_t)i * HWT]);
      *(short8*)&Blds[srow * PAD + scs * 8] = *(const short8*)tmp;
    }
    __syncthreads();

    short8 af[2], bf[2];
#pragma unroll
    for (int mi = 0; mi < 2; ++mi)
      af[mi] = *(const short8*)&Alds[(wm + mi * 16 + lrow) * PAD + cw8];
#pragma unroll
    for (int ni = 0; ni < 2; ++ni)
      bf[ni] = *(const short8*)&Blds[(wn + ni * 16 + lrow) * PAD + cw8];
#pragma unroll
    for (int mi = 0; mi < 2; ++mi)
#pragma unroll
      for (int ni = 0; ni < 2; ++ni)
        acc[mi][ni] = __builtin_amdgcn_mfma_f32_16x16x32_bf16(
            af[mi], bf[ni], acc[mi][ni], 0, 0, 0);
  }

  const int row4 = (lane >> 4) * 4;
#pragma unroll
  for (int mi = 0; mi < 2; ++mi) {
    const int o0 = m0 + wm + mi * 16 + row4;   // quad of consecutive o
    const int t3 = o0 >> 8, c0 = o0 & 255;
    const int head = c0 >> 5, d0 = c0 & 31;
    const float sc = (t3 == 0) ? SCALE : 1.f;
    float bv[4];
#pragma unroll
    for (int r = 0; r < 4; ++r) bv[r] = qkv_b[o0 + r];
    if (t3 == 1) {
      // kT8: ((bn*4 + d0/8) * HWT + hw) * 8 + (d0&7)
      _Float16* base = qh + (size_t)QKV_ELEMS +
                       ((size_t)(b * NH + head) * 4 + (d0 >> 3)) * (HWT * 8) +
                       (d0 & 7);
#pragma unroll
      for (int ni = 0; ni < 2; ++ni) {
        const int hw = n0 + wn + ni * 16 + lrow;
        half4v pack;
#pragma unroll
        for (int r = 0; r < 4; ++r)
          pack[r] = (_Float16)(acc[mi][ni][r] + bv[r]);
        *(half4v*)(base + (size_t)hw * 8) = pack;
      }
    } else {
      _Float16* base = qh + (size_t)t3 * QKV_ELEMS +
                       (size_t)(b * NH + head) * HWT * 32 + d0;
#pragma unroll
      for (int ni = 0; ni < 2; ++ni) {
        const int hw = n0 + wn + ni * 16 + lrow;
        half4v pack;
#pragma unroll
        for (int r = 0; r < 4; ++r)
          pack[r] = (_Float16)((acc[mi][ni][r] + bv[r]) * sc);
        *(half4v*)(base + (size_t)hw * 32) = pack;
      }
    }
  }
}

// ---------------------------------------------------------------------------
// gemm_proj: BM=32 x BN=64 x BK=32. A = proj_w f32 (reg-converted, padded
// LDS); B = att_t bf16 via global_load_lds (linear + XOR swizzle).
// Epilogue -> fp32 out (b,o,hw) + bias. Grid (49, 8, 2).
// R18 PROBE: launched 5x (idempotent rewrite of out).
// ---------------------------------------------------------------------------
__global__ __launch_bounds__(256) void gemm_proj_k(
    const ushort* __restrict__ att_t, const float* __restrict__ proj_w,
    const float* __restrict__ proj_b, float* __restrict__ outp) {
  __shared__ ushort Alds[32 * PAD];
  __shared__ ushort Blds[64 * 32];

  const int t  = threadIdx.x;
  const int m0 = blockIdx.y * 32;
  const int n0 = blockIdx.x * 64;
  const int b  = blockIdx.z;

  const ushort* Bb = att_t + (size_t)b * HWT * CCH;

  const int lane = t & 63, wid = t >> 6;
  const int wm = (wid >> 1) * 16, wn = (wid & 1) * 32;
  const int lrow = lane & 15;
  const int cwant = lane >> 4;
  const int cw8 = cwant * 8;
  const int csw = (cwant ^ ((lrow >> 1) & 3)) * 8;   // B (gload_lds) swizzle

  const int srow   = t >> 2;    // B staging row
  const int scslot = t & 3;
  const int wlds   = wid << 9;

  const int alr = t >> 3;       // A staging: 32 rows x 8 quad-chunks
  const int ac4 = t & 7;

  f32x4 acc[2];
  acc[0] = (f32x4){0.f, 0.f, 0.f, 0.f};
  acc[1] = (f32x4){0.f, 0.f, 0.f, 0.f};

  for (int k0 = 0; k0 < CCH; k0 += 32) {
    __syncthreads();
    // A stage: proj_w[m0+alr][k0+ac4*4 ..+4] f32 -> bf16
    {
      const float4 v0 =
          *(const float4*)(proj_w + (size_t)(m0 + alr) * CCH + k0 + ac4 * 4);
      ushort tmp[4];
      tmp[0] = f2bf(v0.x); tmp[1] = f2bf(v0.y);
      tmp[2] = f2bf(v0.z); tmp[3] = f2bf(v0.w);
      *(short4v*)&Alds[alr * PAD + ac4 * 4] = *(const short4v*)tmp;
    }
    // B stage: global_load_lds, pre-swizzled source
    {
      const int csrc = (scslot ^ ((srow >> 1) & 3)) * 8;
      const ushort* gpb = Bb + (size_t)(n0 + srow) * CCH + k0 + csrc;
      ushort* lpb = Blds + wlds;
      __builtin_amdgcn_global_load_lds(
          (const __attribute__((address_space(1))) void*)gpb,
          (__attribute__((address_space(3))) void*)lpb, 16, 0, 0);
    }
    __syncthreads();

    short8 af, bf[2];
    af = *(const short8*)&Alds[(wm + lrow) * PAD + cw8];
#pragma unroll
    for (int ni = 0; ni < 2; ++ni)
      bf[ni] = *(const short8*)&Blds[(wn + ni * 16 + lrow) * 32 + csw];
#pragma unroll
    for (int ni = 0; ni < 2; ++ni)
      acc[ni] = __builtin_amdgcn_mfma_f32_16x16x32_bf16(af, bf[ni], acc[ni],
                                                        0, 0, 0);
  }

  const int row4 = (lane >> 4) * 4;
#pragma unroll
  for (int r = 0; r < 4; ++r) {
    const int o = m0 + wm + row4 + r;
    const float bvv = proj_b[o];
#pragma unroll
    for (int ni = 0; ni < 2; ++ni) {
      const int hw = n0 + wn + ni * 16 + lrow;
      outp[((size_t)b * CCH + o) * HWT + hw] = acc[ni][r] + bvv;
    }
  }
}

// ---------------------------------------------------------------------------
// attn_v8 (R16, passing, unchanged): phase A batched QK; phase B guard-free
// j split across 2 waves with batch-prefetched 16B V gathers; LDS merge.
// ---------------------------------------------------------------------------
__global__ __launch_bounds__(128, 5) void attn_v8_k(
    const _Float16* __restrict__ q_h, const _Float16* __restrict__ kt8,
    const _Float16* __restrict__ v_h, const float* __restrict__ relbias,
    const ushort* __restrict__ src16, ushort* __restrict__ att_t) {
  // bijective XCD swizzle (3136 % 8 == 0): each XCD owns 2 bn slices
  const int id  = blockIdx.x;
  const int idx = (id & 7) * 392 + (id >> 3);
  const int bn  = idx / 196;
  const int g   = idx % 196;
  const int px0 = g * 16;
  const int b = bn >> 3, n = bn & 7;

  __shared__ float bias_s[169];
  __shared__ uint32_t as_lds[16 * 49];
  __shared__ float part_lds[64][8];

  const int tid = threadIdx.x;
  for (int i = tid; i < 169; i += 128) bias_s[i] = relbias[i * NH + n];
  __syncthreads();

  const int wid = tid >> 6, lane = tid & 63;
  const int jc = lane < 49 ? lane : 48;
  const int jbias = (jc / 7) * 13 + jc % 7;   // per-lane constant

  const _Float16* kb = kt8 + (size_t)bn * 4 * HWT * 8;
  const _Float16* vb = v_h + (size_t)bn * HWT * 32;
  const _Float16* qb = q_h + (size_t)bn * HWT * 32;

  const int pxw = px0 + wid * 8;

  // ---- hoisted: src16 + bias index for all 8 px of this wave ----
  int sv[8], bb[8];
#pragma unroll
  for (int p = 0; p < 8; ++p) {
    const int px = pxw + p;
    const int h = px / WIMG, w = px % WIMG;
    int ph = h - 3; ph = ph < 0 ? 0 : (ph > 49 ? 49 : ph);
    int pw = w - 3; pw = pw < 0 ? 0 : (pw > 49 ? 49 : pw);
    const int l = ph * 50 + pw;
    const int bih = (h < 3) ? h : ((h < 53) ? 3 : h - 49);
    const int biw = (w < 3) ? w : ((w < 53) ? 3 : w - 49);
    bb[p] = bih * 13 + biw + jbias;
    sv[p] = (int)src16[l * 49 + jc];             // coalesced 98B run
  }

  // ---- Phase A: 4 batches of 2 px ----
#pragma unroll
  for (int batch = 0; batch < 4; ++batch) {
    union V16 { uint4 u; half2v h2[4]; };
    V16 K[2][4];
#pragma unroll
    for (int p = 0; p < 2; ++p)
#pragma unroll
      for (int dq = 0; dq < 4; ++dq)
        K[p][dq].u =
            *(const uint4*)(kb + ((size_t)dq * HWT + sv[batch * 2 + p]) * 8);

#pragma unroll
    for (int p = 0; p < 2; ++p) {
      const int pp = batch * 2 + p;
      const int pxu = __builtin_amdgcn_readfirstlane(pxw + pp);
      union V64 { uint4 u[4]; half2v hv[16]; };
      V64 Q;                                      // uniform -> scalar loads
      const uint4* qp = (const uint4*)(qb + (size_t)pxu * 32);
#pragma unroll
      for (int i = 0; i < 4; ++i) Q.u[i] = qp[i];
      const float bvv = bias_s[bb[pp]];

      float a0 = 0.f, a1 = 0.f, a2 = 0.f, a3 = 0.f;
#if HAVE_FDOT2
#pragma unroll
      for (int i = 0; i < 4; ++i) {
        a0 = __builtin_amdgcn_fdot2(K[p][0].h2[i], Q.hv[i],      a0, false);
        a1 = __builtin_amdgcn_fdot2(K[p][1].h2[i], Q.hv[4 + i],  a1, false);
        a2 = __builtin_amdgcn_fdot2(K[p][2].h2[i], Q.hv[8 + i],  a2, false);
        a3 = __builtin_amdgcn_fdot2(K[p][3].h2[i], Q.hv[12 + i], a3, false);
      }
#else
#pragma unroll
      for (int i = 0; i < 4; ++i) {
        a0 += (float)K[p][0].h2[i][0] * (float)Q.hv[i][0] +
              (float)K[p][0].h2[i][1] * (float)Q.hv[i][1];
        a1 += (float)K[p][1].h2[i][0] * (float)Q.hv[4 + i][0] +
              (float)K[p][1].h2[i][1] * (float)Q.hv[4 + i][1];
        a2 += (float)K[p][2].h2[i][0] * (float)Q.hv[8 + i][0] +
              (float)K[p][2].h2[i][1] * (float)Q.hv[8 + i][1];
        a3 += (float)K[p][3].h2[i][0] * (float)Q.hv[12 + i][0] +
              (float)K[p][3].h2[i][1] * (float)Q.hv[12 + i][1];
      }
#endif
      const float a = (a0 + a1) + (a2 + a3) + bvv;
      union { _Float16 hh; uint16_t us; } cv;
      cv.hh = (_Float16)a;
      if (lane < 49)
        as_lds[(wid * 8 + pp) * 49 + lane] = ((uint32_t)sv[pp] << 16) | cv.us;
    }
  }
  __syncthreads();

  // ---- Phase B: lane = (px in [0,16), oc4 in [0,4)); guard-free j split.
  // wave0: j 0..23 (3x8); wave1: j 24..47 (3x8) + uniform extra j=48.
  const int pxb = lane >> 2, oc4 = lane & 3;
  const _Float16* vbase = vb + oc4 * 8;     // 16B = 8 channels per lane
  const uint32_t* arow = &as_lds[pxb * 49];
  const int jbase = wid * 24;

  float acc[8];
#pragma unroll
  for (int c = 0; c < 8; ++c) acc[c] = 0.f;

#pragma unroll
  for (int bt = 0; bt < 3; ++bt) {
    uint32_t u[8];
#pragma unroll
    for (int i = 0; i < 8; ++i) u[i] = arow[jbase + bt * 8 + i];
    half8v vv[8];
#pragma unroll
    for (int i = 0; i < 8; ++i)
      vv[i] = *(const half8v*)(vbase + (size_t)(u[i] >> 16) * 32);
#pragma unroll
    for (int i = 0; i < 8; ++i) {
      union { uint16_t us; _Float16 hh; } cv;
      cv.us = (uint16_t)(u[i] & 0xffffu);
      const float a = (float)cv.hh;
#pragma unroll
      for (int c = 0; c < 8; ++c) acc[c] += a * (float)vv[i][c];  // fma_mix
    }
  }
  if (wid == 1) {                           // wave-uniform extra: j = 48
    const uint32_t u = arow[48];
    union { uint16_t us; _Float16 hh; } cv;
    cv.us = (uint16_t)(u & 0xffffu);
    const float a = (float)cv.hh;
    const half8v vv = *(const half8v*)(vbase + (size_t)(u >> 16) * 32);
#pragma unroll
    for (int c = 0; c < 8; ++c) acc[c] += a * (float)vv[c];
  }

  if (wid == 1) {
#pragma unroll
    for (int c = 0; c < 8; ++c) part_lds[lane][c] = acc[c];
  }
  __syncthreads();
  if (wid == 0) {
#pragma unroll
    for (int c = 0; c < 8; ++c) acc[c] += part_lds[lane][c];
    ushort tmp[8];
#pragma unroll
    for (int c = 0; c < 8; ++c) tmp[c] = f2bf(acc[c]);
    *(short8*)(att_t + ((size_t)b * HWT + px0 + pxb) * CCH + n * 32 + oc4 * 8) =
        *(const short8*)tmp;
  }
}

// ---------------------------------------------------------------------------
extern "C" void kernel_launch(void* const* d_in, const int* in_sizes, int n_in,
                              void* d_out, int out_size, void* d_ws, size_t ws_size,
                              hipStream_t stream) {
  const float* x       = (const float*)d_in[0];
  const float* qkv_w   = (const float*)d_in[1];
  const float* qkv_b   = (const float*)d_in[2];
  const float* proj_w  = (const float*)d_in[3];
  const float* proj_b  = (const float*)d_in[4];
  const float* relbias = (const float*)d_in[5];
  float* out = (float*)d_out;

  char* wsb = (char*)d_ws;
  _Float16* qh    = (_Float16*)wsb;                     // q fp16 (bn,hw,d)
  _Float16* kt8   = qh + (size_t)QKV_ELEMS;             // kT fp16 (bn,d/8,hw,8)
  _Float16* vh    = qh + (size_t)2 * QKV_ELEMS;         // v fp16 (bn,hw,d)
  ushort*   src16 = (ushort*)(wsb + (size_t)3 * QKV_ELEMS * 2); // u16 table
  ushort*   att_t = src16 + 122512;                     // bf16 (b,hw,c), 16B-aligned

  // R18 PROBE: 5x each GEMM (idempotent); dur = base + 4*(gqkv+g) + 4*(gproj+g)
  for (int rep = 0; rep < 5; ++rep) {
    hipLaunchKernelGGL(gemm_qkv_k, dim3(49, 13, 2), dim3(256), 0, stream,
                       x, qkv_w, qkv_b, qh, src16);
  }
  hipLaunchKernelGGL(attn_v8_k, dim3(3136), dim3(128), 0, stream,
                     qh, kt8, vh, relbias, src16, att_t);
  for (int rep = 0; rep < 5; ++rep) {
    hipLaunchKernelGGL(gemm_proj_k, dim3(49, 8, 2), dim3(256), 0, stream,
                       att_t, proj_w, proj_b, out);
  }
}

// Round 19
// 49.343 us; speedup vs baseline: 2.9723x; 2.9723x over previous
//
#include <hip/hip_runtime.h>
#include <cstddef>
#include <cstdint>

#define HWT   3136        // 56*56
#define WIMG  56
#define CCH   256
#define NH    8
#define QKV_ELEMS (16 * HWT * 32)   // per-tensor q/k/v elements
#define SCALE 0.17677669529663687f  // 32^-0.5
#define PADK  136   // 128+8 elems: 272B row stride, 16B-aligned, slot-cycling

typedef __attribute__((ext_vector_type(8))) short short8;
typedef __attribute__((ext_vector_type(4))) short short4v;
typedef __attribute__((ext_vector_type(4))) float f32x4;
typedef _Float16 half2v __attribute__((ext_vector_type(2)));
typedef _Float16 half4v __attribute__((ext_vector_type(4)));
typedef _Float16 half8v __attribute__((ext_vector_type(8)));

#if defined(__has_builtin)
#if __has_builtin(__builtin_amdgcn_fdot2)
#define HAVE_FDOT2 1
#endif
#endif
#ifndef HAVE_FDOT2
#define HAVE_FDOT2 0
#endif

__device__ __forceinline__ ushort f2bf(float f) {
  union { float f; uint32_t u; } v; v.f = f;
  uint32_t u = v.u;
  u += 0x7fffu + ((u >> 16) & 1u);   // round-to-nearest-even
  return (ushort)(u >> 16);
}

// ---------------------------------------------------------------------------
// gemm_qkv: fused prep + qkv GEMM, BK=128 (4 barriers/block, was 16).
// Grid (49, 13, 2). y==12: src16 builder slice (z==0).
// y<12: BM=64 x BN=64 MFMA GEMM; A=qkv_w f32 reg-converted; B=x f32
// reg-transposed+converted. Padded LDS rows (PADK). Epilogue unchanged:
// fp16 q*scale / kT8 / v. Same K-chunk order as BK=32 -> bit-identical.
// ---------------------------------------------------------------------------
__global__ __launch_bounds__(256) void gemm_qkv_k(
    const float* __restrict__ x, const float* __restrict__ qkv_w,
    const float* __restrict__ qkv_b, _Float16* __restrict__ qh,
    ushort* __restrict__ src16) {
  if (blockIdx.y == 12) {            // src16 builder slice
    if (blockIdx.z == 0) {
      for (int e = blockIdx.x * 256 + threadIdx.x; e < 2500 * 49;
           e += 49 * 256) {
        int sp = e / 2500;
        int pos = e - sp * 2500;
        int si = pos / 50;
        int sj = pos - si * 50;
        src16[e] = (ushort)((si + sp / 7) * WIMG + sj + sp % 7);
      }
    }
    return;
  }

  __shared__ ushort Alds[64 * PADK];
  __shared__ ushort Blds[64 * PADK];

  const int t  = threadIdx.x;
  const int m0 = blockIdx.y * 64;
  const int n0 = blockIdx.x * 64;
  const int b  = blockIdx.z;

  const float* xb = x + (size_t)b * CCH * HWT;

  const int lane = t & 63, wid = t >> 6;
  const int wm = (wid >> 1) * 32, wn = (wid & 1) * 32;
  const int lrow = lane & 15;
  const int cw8  = (lane >> 4) * 8;

  const int srow = t >> 2;   // 0..63
  const int sc   = t & 3;

  f32x4 acc[2][2];
#pragma unroll
  for (int i = 0; i < 2; ++i)
#pragma unroll
    for (int j = 0; j < 2; ++j) acc[i][j] = (f32x4){0.f, 0.f, 0.f, 0.f};

  for (int k0 = 0; k0 < CCH; k0 += 128) {
    __syncthreads();
    // A stage: qkv_w rows -> bf16, 4 chunks of 8 elems per thread
#pragma unroll
    for (int it = 0; it < 4; ++it) {
      const int col = sc * 8 + it * 32;
      const float* ap = qkv_w + (size_t)(m0 + srow) * CCH + k0 + col;
      const float4 v0 = *(const float4*)ap;
      const float4 v1 = *(const float4*)(ap + 4);
      ushort tmp[8];
      tmp[0] = f2bf(v0.x); tmp[1] = f2bf(v0.y);
      tmp[2] = f2bf(v0.z); tmp[3] = f2bf(v0.w);
      tmp[4] = f2bf(v1.x); tmp[5] = f2bf(v1.y);
      tmp[6] = f2bf(v1.z); tmp[7] = f2bf(v1.w);
      *(short8*)&Alds[srow * PADK + col] = *(const short8*)tmp;
    }
    // B stage (transpose): x[k0+col+i][n0+srow] f32 -> bf16
#pragma unroll
    for (int it = 0; it < 4; ++it) {
      const int col = sc * 8 + it * 32;
      const float* bp = xb + (size_t)(k0 + col) * HWT + n0 + srow;
      ushort tmp[8];
#pragma unroll
      for (int i = 0; i < 8; ++i) tmp[i] = f2bf(bp[(size_t)i * HWT]);
      *(short8*)&Blds[srow * PADK + col] = *(const short8*)tmp;
    }
    __syncthreads();

#pragma unroll
    for (int ks = 0; ks < 4; ++ks) {
      const int co = cw8 + ks * 32;
      short8 af[2], bf[2];
#pragma unroll
      for (int mi = 0; mi < 2; ++mi)
        af[mi] = *(const short8*)&Alds[(wm + mi * 16 + lrow) * PADK + co];
#pragma unroll
      for (int ni = 0; ni < 2; ++ni)
        bf[ni] = *(const short8*)&Blds[(wn + ni * 16 + lrow) * PADK + co];
#pragma unroll
      for (int mi = 0; mi < 2; ++mi)
#pragma unroll
        for (int ni = 0; ni < 2; ++ni)
          acc[mi][ni] = __builtin_amdgcn_mfma_f32_16x16x32_bf16(
              af[mi], bf[ni], acc[mi][ni], 0, 0, 0);
    }
  }

  const int row4 = (lane >> 4) * 4;
#pragma unroll
  for (int mi = 0; mi < 2; ++mi) {
    const int o0 = m0 + wm + mi * 16 + row4;   // quad of consecutive o
    const int t3 = o0 >> 8, c0 = o0 & 255;
    const int head = c0 >> 5, d0 = c0 & 31;
    const float sc2 = (t3 == 0) ? SCALE : 1.f;
    float bv[4];
#pragma unroll
    for (int r = 0; r < 4; ++r) bv[r] = qkv_b[o0 + r];
    if (t3 == 1) {
      // kT8: ((bn*4 + d0/8) * HWT + hw) * 8 + (d0&7)
      _Float16* base = qh + (size_t)QKV_ELEMS +
                       ((size_t)(b * NH + head) * 4 + (d0 >> 3)) * (HWT * 8) +
                       (d0 & 7);
#pragma unroll
      for (int ni = 0; ni < 2; ++ni) {
        const int hw = n0 + wn + ni * 16 + lrow;
        half4v pack;
#pragma unroll
        for (int r = 0; r < 4; ++r)
          pack[r] = (_Float16)(acc[mi][ni][r] + bv[r]);
        *(half4v*)(base + (size_t)hw * 8) = pack;
      }
    } else {
      _Float16* base = qh + (size_t)t3 * QKV_ELEMS +
                       (size_t)(b * NH + head) * HWT * 32 + d0;
#pragma unroll
      for (int ni = 0; ni < 2; ++ni) {
        const int hw = n0 + wn + ni * 16 + lrow;
        half4v pack;
#pragma unroll
        for (int r = 0; r < 4; ++r)
          pack[r] = (_Float16)((acc[mi][ni][r] + bv[r]) * sc2);
        *(half4v*)(base + (size_t)hw * 32) = pack;
      }
    }
  }
}

// ---------------------------------------------------------------------------
// gemm_proj: BM=32 x BN=64, BK=128 (4 barriers/block). A=proj_w f32
// reg-converted; B=att_t bf16 reg-staged short8 (no gload_lds/swizzle).
// Epilogue -> fp32 out (b,o,hw) + bias. Grid (49, 8, 2).
// ---------------------------------------------------------------------------
__global__ __launch_bounds__(256) void gemm_proj_k(
    const ushort* __restrict__ att_t, const float* __restrict__ proj_w,
    const float* __restrict__ proj_b, float* __restrict__ outp) {
  __shared__ ushort Alds[32 * PADK];
  __shared__ ushort Blds[64 * PADK];

  const int t  = threadIdx.x;
  const int m0 = blockIdx.y * 32;
  const int n0 = blockIdx.x * 64;
  const int b  = blockIdx.z;

  const ushort* Bb = att_t + (size_t)b * HWT * CCH;

  const int lane = t & 63, wid = t >> 6;
  const int wm = (wid >> 1) * 16, wn = (wid & 1) * 32;
  const int lrow = lane & 15;
  const int cw8 = (lane >> 4) * 8;

  const int arow = t >> 3, ac = t & 7;   // A staging: 32 rows x 8 col-slots
  const int brow = t >> 2, bc = t & 3;   // B staging: 64 rows x 4 col-slots

  f32x4 acc[2];
  acc[0] = (f32x4){0.f, 0.f, 0.f, 0.f};
  acc[1] = (f32x4){0.f, 0.f, 0.f, 0.f};

  for (int k0 = 0; k0 < CCH; k0 += 128) {
    __syncthreads();
    // A stage: proj_w f32 -> bf16, 2 chunks of 8
#pragma unroll
    for (int it = 0; it < 2; ++it) {
      const int col = ac * 8 + it * 64;
      const float* ap = proj_w + (size_t)(m0 + arow) * CCH + k0 + col;
      const float4 v0 = *(const float4*)ap;
      const float4 v1 = *(const float4*)(ap + 4);
      ushort tmp[8];
      tmp[0] = f2bf(v0.x); tmp[1] = f2bf(v0.y);
      tmp[2] = f2bf(v0.z); tmp[3] = f2bf(v0.w);
      tmp[4] = f2bf(v1.x); tmp[5] = f2bf(v1.y);
      tmp[6] = f2bf(v1.z); tmp[7] = f2bf(v1.w);
      *(short8*)&Alds[arow * PADK + col] = *(const short8*)tmp;
    }
    // B stage: att_t bf16 direct 16B loads, 4 chunks of 8
#pragma unroll
    for (int it = 0; it < 4; ++it) {
      const int col = bc * 8 + it * 32;
      *(short8*)&Blds[brow * PADK + col] =
          *(const short8*)(Bb + (size_t)(n0 + brow) * CCH + k0 + col);
    }
    __syncthreads();

#pragma unroll
    for (int ks = 0; ks < 4; ++ks) {
      const int co = cw8 + ks * 32;
      const short8 af = *(const short8*)&Alds[(wm + lrow) * PADK + co];
      short8 bf[2];
#pragma unroll
      for (int ni = 0; ni < 2; ++ni)
        bf[ni] = *(const short8*)&Blds[(wn + ni * 16 + lrow) * PADK + co];
#pragma unroll
      for (int ni = 0; ni < 2; ++ni)
        acc[ni] = __builtin_amdgcn_mfma_f32_16x16x32_bf16(af, bf[ni], acc[ni],
                                                          0, 0, 0);
    }
  }

  const int row4 = (lane >> 4) * 4;
#pragma unroll
  for (int r = 0; r < 4; ++r) {
    const int o = m0 + wm + row4 + r;
    const float bvv = proj_b[o];
#pragma unroll
    for (int ni = 0; ni < 2; ++ni) {
      const int hw = n0 + wn + ni * 16 + lrow;
      outp[((size_t)b * CCH + o) * HWT + hw] = acc[ni][r] + bvv;
    }
  }
}

// ---------------------------------------------------------------------------
// attn_v8 (passing, unchanged): phase A batched QK; phase B guard-free j
// split across 2 waves with batch-prefetched 16B V gathers; LDS merge.
// ---------------------------------------------------------------------------
__global__ __launch_bounds__(128, 5) void attn_v8_k(
    const _Float16* __restrict__ q_h, const _Float16* __restrict__ kt8,
    const _Float16* __restrict__ v_h, const float* __restrict__ relbias,
    const ushort* __restrict__ src16, ushort* __restrict__ att_t) {
  // bijective XCD swizzle (3136 % 8 == 0): each XCD owns 2 bn slices
  const int id  = blockIdx.x;
  const int idx = (id & 7) * 392 + (id >> 3);
  const int bn  = idx / 196;
  const int g   = idx % 196;
  const int px0 = g * 16;
  const int b = bn >> 3, n = bn & 7;

  __shared__ float bias_s[169];
  __shared__ uint32_t as_lds[16 * 49];
  __shared__ float part_lds[64][8];

  const int tid = threadIdx.x;
  for (int i = tid; i < 169; i += 128) bias_s[i] = relbias[i * NH + n];
  __syncthreads();

  const int wid = tid >> 6, lane = tid & 63;
  const int jc = lane < 49 ? lane : 48;
  const int jbias = (jc / 7) * 13 + jc % 7;   // per-lane constant

  const _Float16* kb = kt8 + (size_t)bn * 4 * HWT * 8;
  const _Float16* vb = v_h + (size_t)bn * HWT * 32;
  const _Float16* qb = q_h + (size_t)bn * HWT * 32;

  const int pxw = px0 + wid * 8;

  // ---- hoisted: src16 + bias index for all 8 px of this wave ----
  int sv[8], bb[8];
#pragma unroll
  for (int p = 0; p < 8; ++p) {
    const int px = pxw + p;
    const int h = px / WIMG, w = px % WIMG;
    int ph = h - 3; ph = ph < 0 ? 0 : (ph > 49 ? 49 : ph);
    int pw = w - 3; pw = pw < 0 ? 0 : (pw > 49 ? 49 : pw);
    const int l = ph * 50 + pw;
    const int bih = (h < 3) ? h : ((h < 53) ? 3 : h - 49);
    const int biw = (w < 3) ? w : ((w < 53) ? 3 : w - 49);
    bb[p] = bih * 13 + biw + jbias;
    sv[p] = (int)src16[l * 49 + jc];             // coalesced 98B run
  }

  // ---- Phase A: 4 batches of 2 px ----
#pragma unroll
  for (int batch = 0; batch < 4; ++batch) {
    union V16 { uint4 u; half2v h2[4]; };
    V16 K[2][4];
#pragma unroll
    for (int p = 0; p < 2; ++p)
#pragma unroll
      for (int dq = 0; dq < 4; ++dq)
        K[p][dq].u =
            *(const uint4*)(kb + ((size_t)dq * HWT + sv[batch * 2 + p]) * 8);

#pragma unroll
    for (int p = 0; p < 2; ++p) {
      const int pp = batch * 2 + p;
      const int pxu = __builtin_amdgcn_readfirstlane(pxw + pp);
      union V64 { uint4 u[4]; half2v hv[16]; };
      V64 Q;                                      // uniform -> scalar loads
      const uint4* qp = (const uint4*)(qb + (size_t)pxu * 32);
#pragma unroll
      for (int i = 0; i < 4; ++i) Q.u[i] = qp[i];
      const float bvv = bias_s[bb[pp]];

      float a0 = 0.f, a1 = 0.f, a2 = 0.f, a3 = 0.f;
#if HAVE_FDOT2
#pragma unroll
      for (int i = 0; i < 4; ++i) {
        a0 = __builtin_amdgcn_fdot2(K[p][0].h2[i], Q.hv[i],      a0, false);
        a1 = __builtin_amdgcn_fdot2(K[p][1].h2[i], Q.hv[4 + i],  a1, false);
        a2 = __builtin_amdgcn_fdot2(K[p][2].h2[i], Q.hv[8 + i],  a2, false);
        a3 = __builtin_amdgcn_fdot2(K[p][3].h2[i], Q.hv[12 + i], a3, false);
      }
#else
#pragma unroll
      for (int i = 0; i < 4; ++i) {
        a0 += (float)K[p][0].h2[i][0] * (float)Q.hv[i][0] +
              (float)K[p][0].h2[i][1] * (float)Q.hv[i][1];
        a1 += (float)K[p][1].h2[i][0] * (float)Q.hv[4 + i][0] +
              (float)K[p][1].h2[i][1] * (float)Q.hv[4 + i][1];
        a2 += (float)K[p][2].h2[i][0] * (float)Q.hv[8 + i][0] +
              (float)K[p][2].h2[i][1] * (float)Q.hv[8 + i][1];
        a3 += (float)K[p][3].h2[i][0] * (float)Q.hv[12 + i][0] +
              (float)K[p][3].h2[i][1] * (float)Q.hv[12 + i][1];
      }
#endif
      const float a = (a0 + a1) + (a2 + a3) + bvv;
      union { _Float16 hh; uint16_t us; } cv;
      cv.hh = (_Float16)a;
      if (lane < 49)
        as_lds[(wid * 8 + pp) * 49 + lane] = ((uint32_t)sv[pp] << 16) | cv.us;
    }
  }
  __syncthreads();

  // ---- Phase B: lane = (px in [0,16), oc4 in [0,4)); guard-free j split.
  // wave0: j 0..23 (3x8); wave1: j 24..47 (3x8) + uniform extra j=48.
  const int pxb = lane >> 2, oc4 = lane & 3;
  const _Float16* vbase = vb + oc4 * 8;     // 16B = 8 channels per lane
  const uint32_t* arow = &as_lds[pxb * 49];
  const int jbase = wid * 24;

  float acc[8];
#pragma unroll
  for (int c = 0; c < 8; ++c) acc[c] = 0.f;

#pragma unroll
  for (int bt = 0; bt < 3; ++bt) {
    uint32_t u[8];
#pragma unroll
    for (int i = 0; i < 8; ++i) u[i] = arow[jbase + bt * 8 + i];
    half8v vv[8];
#pragma unroll
    for (int i = 0; i < 8; ++i)
      vv[i] = *(const half8v*)(vbase + (size_t)(u[i] >> 16) * 32);
#pragma unroll
    for (int i = 0; i < 8; ++i) {
      union { uint16_t us; _Float16 hh; } cv;
      cv.us = (uint16_t)(u[i] & 0xffffu);
      const float a = (float)cv.hh;
#pragma unroll
      for (int c = 0; c < 8; ++c) acc[c] += a * (float)vv[i][c];  // fma_mix
    }
  }
  if (wid == 1) {                           // wave-uniform extra: j = 48
    const uint32_t u = arow[48];
    union { uint16_t us; _Float16 hh; } cv;
    cv.us = (uint16_t)(u & 0xffffu);
    const float a = (float)cv.hh;
    const half8v vv = *(const half8v*)(vbase + (size_t)(u >> 16) * 32);
#pragma unroll
    for (int c = 0; c < 8; ++c) acc[c] += a * (float)vv[c];
  }

  if (wid == 1) {
#pragma unroll
    for (int c = 0; c < 8; ++c) part_lds[lane][c] = acc[c];
  }
  __syncthreads();
  if (wid == 0) {
#pragma unroll
    for (int c = 0; c < 8; ++c) acc[c] += part_lds[lane][c];
    ushort tmp[8];
#pragma unroll
    for (int c = 0; c < 8; ++c) tmp[c] = f2bf(acc[c]);
    *(short8*)(att_t + ((size_t)b * HWT + px0 + pxb) * CCH + n * 32 + oc4 * 8) =
        *(const short8*)tmp;
  }
}

// ---------------------------------------------------------------------------
extern "C" void kernel_launch(void* const* d_in, const int* in_sizes, int n_in,
                              void* d_out, int out_size, void* d_ws, size_t ws_size,
                              hipStream_t stream) {
  const float* x       = (const float*)d_in[0];
  const float* qkv_w   = (const float*)d_in[1];
  const float* qkv_b   = (const float*)d_in[2];
  const float* proj_w  = (const float*)d_in[3];
  const float* proj_b  = (const float*)d_in[4];
  const float* relbias = (const float*)d_in[5];
  float* out = (float*)d_out;

  char* wsb = (char*)d_ws;
  _Float16* qh    = (_Float16*)wsb;                     // q fp16 (bn,hw,d)
  _Float16* kt8   = qh + (size_t)QKV_ELEMS;             // kT fp16 (bn,d/8,hw,8)
  _Float16* vh    = qh + (size_t)2 * QKV_ELEMS;         // v fp16 (bn,hw,d)
  ushort*   src16 = (ushort*)(wsb + (size_t)3 * QKV_ELEMS * 2); // u16 table
  ushort*   att_t = src16 + 122512;                     // bf16 (b,hw,c), 16B-aligned

  hipLaunchKernelGGL(gemm_qkv_k, dim3(49, 13, 2), dim3(256), 0, stream,
                     x, qkv_w, qkv_b, qh, src16);
  hipLaunchKernelGGL(attn_v8_k, dim3(3136), dim3(128), 0, stream,
                     qh, kt8, vh, relbias, src16, att_t);
  hipLaunchKernelGGL(gemm_proj_k, dim3(49, 8, 2), dim3(256), 0, stream,
                     att_t, proj_w, proj_b, out);
}